// Round 1
// baseline (4445.054 us; speedup 1.0000x reference)
//
#include <hip/hip_runtime.h>

#define T_STEPS 256
#define BATCH   64
#define HID     1024
#define DIN     512
#define NCLS    1000
#define NBLK    128
#define HSZ     (BATCH * HID)

typedef __attribute__((ext_vector_type(8))) short  short8;  // 8 bf16
typedef __attribute__((ext_vector_type(4))) float  f32x4;   // MFMA C/D
typedef unsigned long long u64;

__device__ __forceinline__ unsigned short rne_bf16(float f) {
    unsigned int u = __builtin_bit_cast(unsigned int, f);
    u += 0x7FFFu + ((u >> 16) & 1u);
    return (unsigned short)(u >> 16);
}
__device__ __forceinline__ float bf16_to_f(unsigned short h) {
    unsigned int u = ((unsigned int)h) << 16;
    return __builtin_bit_cast(float, u);
}

#define MFMA(a, b, c) __builtin_amdgcn_mfma_f32_16x16x32_bf16((a), (b), (c), 0, 0, 0)

// Device-coherent (agent-scope, sc1) state access. Stores write through to the
// coherence point (Infinity Cache); loads force-miss L1/L2. This makes the
// h-state exchange coherent WITHOUT any __threadfence (no buffer_wbl2 /
// buffer_inv full-cache ops). Visibility ordering: __syncthreads drains
// vmcnt(0) (store ack = reached coherence point) before tid0's arrive-atomic.
__device__ __forceinline__ short8 ld_st8(const unsigned short* p) {
    u64 a = __hip_atomic_load((const u64*)p,       __ATOMIC_RELAXED, __HIP_MEMORY_SCOPE_AGENT);
    u64 b = __hip_atomic_load((const u64*)(p + 4), __ATOMIC_RELAXED, __HIP_MEMORY_SCOPE_AGENT);
    union { u64 q[2]; short8 v; } u;
    u.q[0] = a; u.q[1] = b;
    return u.v;
}
__device__ __forceinline__ void st_u32(unsigned short* p, unsigned int v) {
    __hip_atomic_store((unsigned int*)p, v, __ATOMIC_RELAXED, __HIP_MEMORY_SCOPE_AGENT);
}

// ---------------------------------------------------------------------------
// One-hop group barrier (64 members). No fences: state data moves via sc1
// atomics, so only arrival counting is needed. Every block's tid0 polls the
// 8 spread counters itself (removes the block0 fan-in -> gen broadcast hop).
// cnt points at this group's counter bank (8 counters, 32-int stride).
// ---------------------------------------------------------------------------
__device__ __forceinline__ void grid_bar(int* cnt, int bid, int tid, int p) {
    __syncthreads();   // drains vmcnt -> all sc1 state stores are visible
    if (tid == 0) {
        __hip_atomic_fetch_add(&cnt[((bid >> 1) & 7) * 32], 1,
                               __ATOMIC_RELAXED, __HIP_MEMORY_SCOPE_AGENT);
        const int target = 64 * (p + 1);
        for (long it = 0; it < 50000000L; ++it) {
            int s = 0;
#pragma unroll
            for (int i = 0; i < 8; ++i)
                s += __hip_atomic_load(&cnt[i * 32], __ATOMIC_RELAXED,
                                       __HIP_MEMORY_SCOPE_AGENT);
            if (s >= target) break;
        }
        asm volatile("" ::: "memory");   // compiler fence: keep data loads below poll
    }
    __syncthreads();
}

// reduce 8 wave-partials from LDS (+ optional fp32 xproj tile), relu,
// split to bf16 hi/lo, store (device-coherent). red: [wave][m:32][n:34].
__device__ __forceinline__ void reduce_store(const float* red, int tid,
                                             int mbase, int nbase,
                                             unsigned short* ohi, unsigned short* olo,
                                             float* of, const float* xp) {
    const int m = tid >> 4;
    const int n = (tid * 2) & 31;
    float s0, s1;
    if (xp) {
        float2 xi = *(const float2*)(xp + (size_t)(mbase + m) * HID + nbase + n);
        s0 = xi.x; s1 = xi.y;
    } else { s0 = 0.f; s1 = 0.f; }
#pragma unroll
    for (int ww = 0; ww < 8; ++ww) {
        const float* rp = red + ww * 1088 + m * 34 + n;
        s0 += rp[0];
        s1 += rp[1];
    }
    const float v0 = fmaxf(s0, 0.f), v1 = fmaxf(s1, 0.f);
    const unsigned short h0 = rne_bf16(v0), h1 = rne_bf16(v1);
    const unsigned int hp = (unsigned int)h0 | ((unsigned int)h1 << 16);
    const unsigned int lp = (unsigned int)rne_bf16(v0 - bf16_to_f(h0)) |
                            ((unsigned int)rne_bf16(v1 - bf16_to_f(h1)) << 16);
    const size_t o = (size_t)(mbase + m) * HID + nbase + n;
    st_u32(ohi + o, hp);
    st_u32(olo + o, lp);
    if (of) { float2 f2; f2.x = v0; f2.y = v1; *(float2*)(of + o) = f2; }
}

// ---------------------------------------------------------------------------
// Persistent MFMA RNN. 128 blocks x 512 threads (8 waves). bid: z = bid>>6,
// r = bid&63: nbase = (r>>1)*32, mbase = (r&1)*32.
// The grid decomposes into TWO independent groups by mbase parity (r&1):
// every read (h1 rows, h2 rows) stays within the same parity half -> two
// independent 64-member barriers.
// Layer 1: K = 1024 (h1 only; x-projection precomputed into xproj and added
// in reduce_store). Layer 2: K = 2048 (waves 0..3 h1-next, 4..7 h2-cur).
// ---------------------------------------------------------------------------
__global__ __launch_bounds__(512, 2)
void rnn_mfma(const float* __restrict__ xproj,
              const unsigned short* __restrict__ whh0h, const unsigned short* __restrict__ whh0l,
              const unsigned short* __restrict__ wih1h, const unsigned short* __restrict__ wih1l,
              const unsigned short* __restrict__ whh1h, const unsigned short* __restrict__ whh1l,
              unsigned short* h1hi, unsigned short* h1lo,
              unsigned short* h2hi, unsigned short* h2lo,
              float* h2f, int* bar) {
    __shared__ float red[8 * 1088];   // 34.8 KB

    const int bid   = blockIdx.x;
    const int z     = bid >> 6;
    const int r     = bid & 63;
    const int nbase = (r >> 1) * 32;
    const int mbase = (r & 1) * 32;
    const int tid   = threadIdx.x;
    const int w     = tid >> 6;
    const int lane  = tid & 63;
    const int l15   = lane & 15;
    const int kq    = (lane >> 4) * 8;

    int* cnt = bar + (bid & 1) * 256;   // per-parity counter bank

    if (z == 0) {
        // ---- layer 1: K = 1024, wave w owns k in [w*128, w*128+128)
        short8 WH[2][4], WL[2][4];
        const int kb = w * 128;
#pragma unroll
        for (int c = 0; c < 4; ++c)
#pragma unroll
            for (int nt = 0; nt < 2; ++nt) {
                const size_t o = (size_t)(nbase + nt * 16 + l15) * HID + kb + c * 32 + kq;
                WH[nt][c] = *(const short8*)(whh0h + o);
                WL[nt][c] = *(const short8*)(whh0l + o);
            }
        for (int p = 0; p <= T_STEPS; ++p) {
            if (p < T_STEPS) {
                f32x4 acc[2][2] = {};
                const unsigned short* hch = h1hi + (size_t)(p & 1) * HSZ;
                const unsigned short* hcl = h1lo + (size_t)(p & 1) * HSZ;
#pragma unroll
                for (int c = 0; c < 4; ++c) {
                    short8 ah[2], al[2];
#pragma unroll
                    for (int mt = 0; mt < 2; ++mt) {
                        const size_t o = (size_t)(mbase + mt * 16 + l15) * HID + kb + c * 32 + kq;
                        ah[mt] = ld_st8(hch + o);
                        al[mt] = ld_st8(hcl + o);
                    }
#pragma unroll
                    for (int mt = 0; mt < 2; ++mt)
#pragma unroll
                        for (int nt = 0; nt < 2; ++nt) {
                            acc[mt][nt] = MFMA(ah[mt], WH[nt][c], acc[mt][nt]);
                            acc[mt][nt] = MFMA(al[mt], WH[nt][c], acc[mt][nt]);
                            acc[mt][nt] = MFMA(ah[mt], WL[nt][c], acc[mt][nt]);
                        }
                }
#pragma unroll
                for (int mt = 0; mt < 2; ++mt)
#pragma unroll
                    for (int nt = 0; nt < 2; ++nt)
#pragma unroll
                        for (int i = 0; i < 4; ++i)
                            red[w * 1088 + (mt * 16 + (lane >> 4) * 4 + i) * 34 +
                                nt * 16 + l15] = acc[mt][nt][i];
                __syncthreads();
                const size_t ob = (size_t)((p + 1) & 1) * HSZ;
                reduce_store(red, tid, mbase, nbase, h1hi + ob, h1lo + ob, nullptr,
                             xproj + (size_t)p * BATCH * HID);
            }
            grid_bar(cnt, bid, tid, p);
        }
    } else {
        // ---- layer 2: K = 2048 (waves 0..3 = h1-next, 4..7 = h2-cur)
        short8 WH[2][8], WL[2][8];
        const unsigned short* ph = (w < 4) ? wih1h : whh1h;
        const unsigned short* pl = (w < 4) ? wih1l : whh1l;
        const int kb = (w & 3) * 256;
#pragma unroll
        for (int c = 0; c < 8; ++c)
#pragma unroll
            for (int nt = 0; nt < 2; ++nt) {
                const size_t o = (size_t)(nbase + nt * 16 + l15) * HID + kb + c * 32 + kq;
                WH[nt][c] = *(const short8*)(ph + o);
                WL[nt][c] = *(const short8*)(pl + o);
            }
        for (int p = 0; p <= T_STEPS; ++p) {
            if (p >= 1) {
                f32x4 acc[2][2] = {};
                const unsigned short* ash = (w < 4) ? h1hi + (size_t)(p & 1) * HSZ
                                                    : h2hi + (size_t)((p - 1) & 1) * HSZ;
                const unsigned short* asl = (w < 4) ? h1lo + (size_t)(p & 1) * HSZ
                                                    : h2lo + (size_t)((p - 1) & 1) * HSZ;
#pragma unroll
                for (int c = 0; c < 8; ++c) {
                    short8 ah[2], al[2];
#pragma unroll
                    for (int mt = 0; mt < 2; ++mt) {
                        const size_t o = (size_t)(mbase + mt * 16 + l15) * HID + kb + c * 32 + kq;
                        ah[mt] = ld_st8(ash + o);
                        al[mt] = ld_st8(asl + o);
                    }
#pragma unroll
                    for (int mt = 0; mt < 2; ++mt)
#pragma unroll
                        for (int nt = 0; nt < 2; ++nt) {
                            acc[mt][nt] = MFMA(ah[mt], WH[nt][c], acc[mt][nt]);
                            acc[mt][nt] = MFMA(al[mt], WH[nt][c], acc[mt][nt]);
                            acc[mt][nt] = MFMA(ah[mt], WL[nt][c], acc[mt][nt]);
                        }
                }
#pragma unroll
                for (int mt = 0; mt < 2; ++mt)
#pragma unroll
                    for (int nt = 0; nt < 2; ++nt)
#pragma unroll
                        for (int i = 0; i < 4; ++i)
                            red[w * 1088 + (mt * 16 + (lane >> 4) * 4 + i) * 34 +
                                nt * 16 + l15] = acc[mt][nt][i];
                __syncthreads();
                const size_t ob = (size_t)(p & 1) * HSZ;
                reduce_store(red, tid, mbase, nbase, h2hi + ob, h2lo + ob,
                             (p == T_STEPS) ? h2f : nullptr, nullptr);
            }
            grid_bar(cnt, bid, tid, p);
        }
    }
}

// ---------------------------------------------------------------------------
// Bulk x-projection: xproj[t][b][n] = sum_k x[b][t][k] * w_ih0[n][k],
// 3-pass Markidis with on-the-fly fp32->bf16 hi/lo split of x.
// grid (T, 4 n-quarters) x 512; wave w -> 32 cols, all 64 batch rows.
// ---------------------------------------------------------------------------
__global__ __launch_bounds__(512)
void xproj_gemm(const float* __restrict__ x,
                const unsigned short* __restrict__ wh,
                const unsigned short* __restrict__ wl,
                float* __restrict__ xproj) {
    const int t    = blockIdx.x;
    const int nq   = blockIdx.y;
    const int w    = threadIdx.x >> 6;
    const int lane = threadIdx.x & 63;
    const int l15  = lane & 15;
    const int kq   = (lane >> 4) * 8;
    const int n0   = nq * 256 + w * 32;

    f32x4 acc[4][2] = {};
    for (int c = 0; c < 16; ++c) {
        const int k = c * 32 + kq;
        short8 wfh[2], wfl[2];
#pragma unroll
        for (int nt = 0; nt < 2; ++nt) {
            const size_t o = (size_t)(n0 + nt * 16 + l15) * DIN + k;
            wfh[nt] = *(const short8*)(wh + o);
            wfl[nt] = *(const short8*)(wl + o);
        }
#pragma unroll
        for (int mt = 0; mt < 4; ++mt) {
            const float* xr = x + ((size_t)(mt * 16 + l15) * T_STEPS + t) * DIN + k;
            float4 a0 = *(const float4*)xr;
            float4 a1 = *(const float4*)(xr + 4);
            float f[8] = {a0.x, a0.y, a0.z, a0.w, a1.x, a1.y, a1.z, a1.w};
            short8 ah, al;
#pragma unroll
            for (int i = 0; i < 8; ++i) {
                unsigned short h = rne_bf16(f[i]);
                ah[i] = (short)h;
                al[i] = (short)rne_bf16(f[i] - bf16_to_f(h));
            }
#pragma unroll
            for (int nt = 0; nt < 2; ++nt) {
                acc[mt][nt] = MFMA(ah, wfh[nt], acc[mt][nt]);
                acc[mt][nt] = MFMA(al, wfh[nt], acc[mt][nt]);
                acc[mt][nt] = MFMA(ah, wfl[nt], acc[mt][nt]);
            }
        }
    }
    float* op = xproj + (size_t)t * BATCH * HID;
#pragma unroll
    for (int mt = 0; mt < 4; ++mt)
#pragma unroll
        for (int nt = 0; nt < 2; ++nt)
#pragma unroll
            for (int i = 0; i < 4; ++i) {
                const int m = mt * 16 + (lane >> 4) * 4 + i;
                const int n = n0 + nt * 16 + l15;
                op[(size_t)m * HID + n] = acc[mt][nt][i];
            }
}

__global__ void split_w(const float* __restrict__ src,
                        unsigned short* __restrict__ hi,
                        unsigned short* __restrict__ lo, int n) {
    int i = blockIdx.x * 256 + threadIdx.x;
    if (i < n) {
        float v = src[i];
        unsigned short h = rne_bf16(v);
        hi[i] = h;
        lo[i] = rne_bf16(v - bf16_to_f(h));
    }
}

__global__ void zero_kernel(int* __restrict__ p, int n) {
    int i = blockIdx.x * 256 + threadIdx.x;
    if (i < n) p[i] = 0;
}

__global__ void fc_kernel(const float* __restrict__ h2,
                          const float* __restrict__ w_fc,
                          float* __restrict__ out) {
    __shared__ float hs[HID];
    const int b = blockIdx.x;
    for (int i = threadIdx.x; i < HID; i += 256) hs[i] = h2[(size_t)b * HID + i];
    __syncthreads();
    const int c = blockIdx.y * 256 + threadIdx.x;
    if (c < NCLS) {
        const float* w = w_fc + (size_t)c * HID;
        float s = 0.f;
        for (int k = 0; k < HID; k += 4) {
            float4 wv = *(const float4*)(w + k);
            s += wv.x * hs[k] + wv.y * hs[k + 1] + wv.z * hs[k + 2] + wv.w * hs[k + 3];
        }
        out[(size_t)b * NCLS + c] = s;
    }
}

extern "C" void kernel_launch(void* const* d_in, const int* in_sizes, int n_in,
                              void* d_out, int out_size, void* d_ws, size_t ws_size,
                              hipStream_t stream) {
    const float* x     = (const float*)d_in[0];
    const float* w_ih0 = (const float*)d_in[1];
    const float* w_hh0 = (const float*)d_in[2];
    const float* w_ih1 = (const float*)d_in[3];
    const float* w_hh1 = (const float*)d_in[4];
    const float* w_fc  = (const float*)d_in[5];
    float* out = (float*)d_out;

    char* ws = (char*)d_ws;
    size_t off = 0;
    auto alloc = [&](size_t bytes) { char* p = ws + off; off += bytes; return p; };
    float*          xproj = (float*)alloc((size_t)T_STEPS * BATCH * HID * 4);  // 64 MB
    unsigned short* wih0h = (unsigned short*)alloc((size_t)DIN * HID * 2);
    unsigned short* wih0l = (unsigned short*)alloc((size_t)DIN * HID * 2);
    unsigned short* whh0h = (unsigned short*)alloc((size_t)HID * HID * 2);
    unsigned short* whh0l = (unsigned short*)alloc((size_t)HID * HID * 2);
    unsigned short* wih1h = (unsigned short*)alloc((size_t)HID * HID * 2);
    unsigned short* wih1l = (unsigned short*)alloc((size_t)HID * HID * 2);
    unsigned short* whh1h = (unsigned short*)alloc((size_t)HID * HID * 2);
    unsigned short* whh1l = (unsigned short*)alloc((size_t)HID * HID * 2);
    unsigned short* h1hi  = (unsigned short*)alloc(2 * HSZ * 2);
    unsigned short* h1lo  = (unsigned short*)alloc(2 * HSZ * 2);
    unsigned short* h2hi  = (unsigned short*)alloc(2 * HSZ * 2);
    unsigned short* h2lo  = (unsigned short*)alloc(2 * HSZ * 2);
    float*          h2f   = (float*)alloc(HSZ * 4);
    int*            bar   = (int*)alloc(4096);

    // split weights to bf16 hi/lo
    split_w<<<(DIN * HID + 255) / 256, 256, 0, stream>>>(w_ih0, wih0h, wih0l, DIN * HID);
    split_w<<<(HID * HID + 255) / 256, 256, 0, stream>>>(w_hh0, whh0h, whh0l, HID * HID);
    split_w<<<(HID * HID + 255) / 256, 256, 0, stream>>>(w_ih1, wih1h, wih1l, HID * HID);
    split_w<<<(HID * HID + 255) / 256, 256, 0, stream>>>(w_hh1, whh1h, whh1l, HID * HID);

    // bulk x-projection (removes x from the recurrence critical path)
    xproj_gemm<<<dim3(T_STEPS, 4), 512, 0, stream>>>(x, wih0h, wih0l, xproj);

    // zero h states + h2f + barrier (contiguous tail region)
    const int nzero = (4 * (2 * HSZ * 2) + HSZ * 4 + 4096) / 4;
    zero_kernel<<<(nzero + 255) / 256, 256, 0, stream>>>((int*)h1hi, nzero);

    rnn_mfma<<<NBLK, 512, 0, stream>>>(xproj,
                                       whh0h, whh0l,
                                       wih1h, wih1l, whh1h, whh1l,
                                       h1hi, h1lo, h2hi, h2lo, h2f, bar);

    fc_kernel<<<dim3(64, 4), 256, 0, stream>>>(h2f, w_fc, out);
}